// Round 11
// baseline (851.138 us; speedup 1.0000x reference)
//
#include <hip/hip_runtime.h>
#include <hip/hip_bf16.h>

typedef __attribute__((ext_vector_type(8))) short bf16x8_t;
typedef __attribute__((ext_vector_type(4))) float f32x4_t;

__device__ __forceinline__ void gll16(const void* g, void* l) {
  __builtin_amdgcn_global_load_lds((const __attribute__((address_space(1))) void*)g,
                                   (__attribute__((address_space(3))) void*)l, 16, 0, 0);
}
__device__ __forceinline__ void nts(__hip_bfloat16* p, float v) {
  union { __hip_bfloat16 b; short s; } u; u.b = __float2bfloat16(v);
  __builtin_nontemporal_store(u.s, (short*)p);
}
__device__ __forceinline__ void ntf(float* p, float v) {
  __builtin_nontemporal_store(v, p);
}

// ---------------- f32 -> bf16 convert ----------------
__global__ __launch_bounds__(256) void k_cvt(const float* __restrict__ in,
                                             __hip_bfloat16* __restrict__ out, int n) {
  int i = blockIdx.x * 256 + threadIdx.x;
  if (i < n) out[i] = __float2bfloat16(in[i]);
}

// ---------------- cmbp: rpb+mask packed in MFMA C-fragment order ----------------
__global__ __launch_bounds__(256) void k_cmb(const int* __restrict__ rpi,
                                             const float* __restrict__ tab,
                                             const float* __restrict__ mask,
                                             float* __restrict__ cmbp) {
  int idx = blockIdx.x * 256 + threadIdx.x;   // < 64*16*16*256 = 4194304
  int jj = idx & 3, lane = (idx >> 2) & 63, tile = (idx >> 8) & 15;
  int h = (idx >> 12) & 15, w6 = idx >> 16;
  int r = (tile >> 2) * 16 + (lane >> 4) * 4 + jj;
  int c = (tile & 3) * 16 + (lane & 15);
  float v = -1e9f;
  if (r < 49 && c < 49) v = tab[rpi[r * 49 + c] * 16 + h] + mask[w6 * 2401 + r * 49 + c];
  cmbp[idx] = v;
}

// ---------------- layernorm (+optional shift+window-partition), f32 -> bf16 ----------------
template<int PERM>
__global__ __launch_bounds__(256) void k_ln(const float* __restrict__ in,
                                            const float* __restrict__ g,
                                            const float* __restrict__ bta,
                                            __hip_bfloat16* __restrict__ out) {
  int token = blockIdx.x;
  int t = threadIdx.x;
  const float2 v = ((const float2*)(in + (size_t)token * 512))[t];
  float s = v.x + v.y, sq = v.x * v.x + v.y * v.y;
  #pragma unroll
  for (int d = 1; d < 64; d <<= 1) { s += __shfl_xor(s, d); sq += __shfl_xor(sq, d); }
  __shared__ float ps[4], pq[4];
  int w = t >> 6;
  if ((t & 63) == 0) { ps[w] = s; pq[w] = sq; }
  __syncthreads();
  s  = ps[0] + ps[1] + ps[2] + ps[3];
  sq = pq[0] + pq[1] + pq[2] + pq[3];
  float mean = s * (1.f / 512.f);
  float inv = rsqrtf(sq * (1.f / 512.f) - mean * mean + 1e-5f);
  size_t dst;
  if (PERM) {
    int b = token / 3136, p = token - b * 3136;
    int i = p / 56, j = p - i * 56;
    int gi = (i + 53) % 56, gj = (j + 53) % 56;       // (i-3) mod 56
    dst = ((size_t)(((b * 64) + (gi / 7) * 8 + (gj / 7)) * 49) + (gi % 7) * 7 + (gj % 7)) * 512;
  } else {
    dst = (size_t)token * 512;
  }
  int c = t * 2;
  union { __hip_bfloat16 h[2]; unsigned int u; } pk;
  pk.h[0] = __float2bfloat16((v.x - mean) * inv * g[c] + bta[c]);
  pk.h[1] = __float2bfloat16((v.y - mean) * inv * g[c + 1] + bta[c + 1]);
  __builtin_nontemporal_store(pk.u, (unsigned int*)&out[dst + c]);
}

// ---------------- MFMA windowed attention: one wave per (window, head) ----------------
__global__ __launch_bounds__(256) void k_attn(const __hip_bfloat16* __restrict__ qkv,
                                              const float* __restrict__ cmbp,
                                              __hip_bfloat16* __restrict__ o) {
  __shared__ __align__(16) __hip_bfloat16 vt_all[4 * 32 * 72];
  __shared__ __align__(16) __hip_bfloat16 P_all[4 * 64 * 72];
  const int t = threadIdx.x, l = t & 63, w = t >> 6;
  const int bw = blockIdx.x;
  const int head = blockIdx.y * 4 + w;
  const int rr = l & 15, g = l >> 4;
  __hip_bfloat16* vt = vt_all + w * (32 * 72);
  __hip_bfloat16* P  = P_all  + w * (64 * 72);
  const __hip_bfloat16* base = qkv + (size_t)bw * 49 * 1536 + head * 32;
  const bf16x8_t zero8 = {};

  { int d = l >> 1, sg = (l & 1) * 8;
    *(bf16x8_t*)(vt + d * 72 + 48 + sg) = zero8; }
  __builtin_amdgcn_sched_barrier(0);
  #pragma unroll
  for (int it = 0; it < 4; ++it) {
    int idx = l + it * 64;
    if (idx < 196) {
      int j = idx >> 2, sg = (idx & 3) * 8;
      bf16x8_t vv = *(const bf16x8_t*)(base + 1024 + (size_t)j * 1536 + sg);
      #pragma unroll
      for (int s2 = 0; s2 < 8; ++s2) vt[(sg + s2) * 72 + j] = ((__hip_bfloat16*)&vv)[s2];
    }
  }
  bf16x8_t aq[4], bk[4];
  #pragma unroll
  for (int m = 0; m < 4; ++m) {
    int row = m * 16 + rr;
    aq[m] = (row < 49) ? *(const bf16x8_t*)(base + (size_t)row * 1536 + g * 8) : zero8;
    bk[m] = (row < 49) ? *(const bf16x8_t*)(base + 512 + (size_t)row * 1536 + g * 8) : zero8;
  }
  const float4* cp = (const float4*)(cmbp + (size_t)((bw & 63) * 16 + head) * 4096);
  f32x4_t S[4][4];
  #pragma unroll
  for (int tm = 0; tm < 4; ++tm)
    #pragma unroll
    for (int tn = 0; tn < 4; ++tn) {
      float4 cv = cp[(tm * 4 + tn) * 64 + l];
      f32x4_t c0 = { cv.x, cv.y, cv.z, cv.w };
      S[tm][tn] = __builtin_amdgcn_mfma_f32_16x16x32_bf16(aq[tm], bk[tn], c0, 0, 0, 0);
    }
  float sm[4][4];
  #pragma unroll
  for (int tm = 0; tm < 4; ++tm) {
    #pragma unroll
    for (int jj = 0; jj < 4; ++jj) {
      float v = fmaxf(fmaxf(S[tm][0][jj], S[tm][1][jj]), fmaxf(S[tm][2][jj], S[tm][3][jj]));
      v = fmaxf(v, __shfl_xor(v, 1));
      v = fmaxf(v, __shfl_xor(v, 2));
      v = fmaxf(v, __shfl_xor(v, 4));
      v = fmaxf(v, __shfl_xor(v, 8));
      float s = 0.f;
      #pragma unroll
      for (int tn = 0; tn < 4; ++tn) {
        float e = __expf(S[tm][tn][jj] - v);
        S[tm][tn][jj] = e;
        s += e;
      }
      s += __shfl_xor(s, 1); s += __shfl_xor(s, 2); s += __shfl_xor(s, 4); s += __shfl_xor(s, 8);
      sm[tm][jj] = s;
    }
  }
  #pragma unroll
  for (int tm = 0; tm < 4; ++tm)
    #pragma unroll
    for (int tn = 0; tn < 4; ++tn)
      #pragma unroll
      for (int jj = 0; jj < 4; ++jj)
        P[(tm * 16 + g * 4 + jj) * 72 + tn * 16 + rr] = __float2bfloat16(S[tm][tn][jj]);

  f32x4_t O[4][2] = {};
  #pragma unroll
  for (int ks = 0; ks < 2; ++ks) {
    bf16x8_t pa[4], vb[2];
    #pragma unroll
    for (int tm = 0; tm < 4; ++tm)
      pa[tm] = *(const bf16x8_t*)(P + (tm * 16 + rr) * 72 + ks * 32 + g * 8);
    #pragma unroll
    for (int tn = 0; tn < 2; ++tn)
      vb[tn] = *(const bf16x8_t*)(vt + (tn * 16 + rr) * 72 + ks * 32 + g * 8);
    #pragma unroll
    for (int tm = 0; tm < 4; ++tm)
      #pragma unroll
      for (int tn = 0; tn < 2; ++tn)
        O[tm][tn] = __builtin_amdgcn_mfma_f32_16x16x32_bf16(pa[tm], vb[tn], O[tm][tn], 0, 0, 0);
  }
  #pragma unroll
  for (int tm = 0; tm < 4; ++tm) {
    #pragma unroll
    for (int jj = 0; jj < 4; ++jj) {
      int r = tm * 16 + g * 4 + jj;
      if (r < 49) {
        float rcp = 1.f / sm[tm][jj];
        size_t ob = ((size_t)bw * 49 + r) * 512 + head * 32;
        nts(&o[ob + rr],      O[tm][0][jj] * rcp);
        nts(&o[ob + 16 + rr], O[tm][1][jj] * rcp);
      }
    }
  }
}

// ---------------- 256x256 bf16 GEMM: BK=64 quadrant-phase pipeline, counted vmcnt(4) ----------------
// Loop identical to round-9 (verified). Epilogue: non-temporal stores (avoid L2 write-thrash
// that evicts staging panels), EP1 token math hoisted per-row.
template<int EP>
__global__ __launch_bounds__(512, 2) void gemm256(const __hip_bfloat16* __restrict__ A,
                                                  const __hip_bfloat16* __restrict__ Bw,
                                                  int K, int Ncols, int nNB,
                                                  const float* __restrict__ bias,
                                                  __hip_bfloat16* __restrict__ obf,
                                                  const float* __restrict__ resid,
                                                  float* __restrict__ ofp) {
  __shared__ __align__(16) char LDS[131072];  // A: [2buf][2half][16KB] at 0; B same at 65536
  const int nwg = gridDim.x, orig = blockIdx.x;
  const int q8 = nwg >> 3, r8 = nwg & 7;
  const int xcd = orig & 7, lin = orig >> 3;
  const int wgid = (xcd < r8 ? xcd * (q8 + 1) : r8 * (q8 + 1) + (xcd - r8) * q8) + lin;
  const int bx = wgid / nNB, by = wgid - bx * nNB;
  const int m0 = bx * 256, n0 = by * 256;
  const int t = threadIdx.x, l = t & 63, w = t >> 6;
  const int wr = w >> 2, wc = w & 3;
  const int rr = l & 15, kq = l >> 4;
  const int swzo = (kq * 16) ^ ((rr & 8) << 2);

  int rs0, cs0, rs1, cs1;
  { int d = t * 16;  rs0 = (d >> 10) * 16 + ((d >> 6) & 15);
    cs0 = ((d & 63) ^ (((d >> 9) & 1) << 5)) >> 1; }
  { int d = 8192 + t * 16; int dd = d & 8191;
    rs1 = (dd >> 10) * 16 + ((dd >> 6) & 15);
    cs1 = 32 + (((d & 63) ^ (((d >> 9) & 1) << 5)) >> 1); }
  const __hip_bfloat16* gA = A + (size_t)m0 * K;
  const __hip_bfloat16* gB = Bw + (size_t)n0 * K;

  auto stageA = [&](int T, int h) {
    char* dst = LDS + (T & 1) * 32768 + h * 16384 + t * 16;
    const size_t kb = (size_t)T * 64;
    gll16(gA + (size_t)(h * 128 + rs0) * K + kb + cs0, dst);
    gll16(gA + (size_t)(h * 128 + rs1) * K + kb + cs1, dst + 8192);
  };
  auto stageB = [&](int T, int h) {
    char* dst = LDS + 65536 + (T & 1) * 32768 + h * 16384 + t * 16;
    const size_t kb = (size_t)T * 64;
    gll16(gB + (size_t)(h * 128 + rs0) * K + kb + cs0, dst);
    gll16(gB + (size_t)(h * 128 + rs1) * K + kb + cs1, dst + 8192);
  };

  auto ldA = [&](bf16x8_t (&a)[4][2], int buf, int mq) {
    const char* b = LDS + buf * 32768 + wr * 16384;
    #pragma unroll
    for (int m = 0; m < 4; ++m)
      #pragma unroll
      for (int ks = 0; ks < 2; ++ks)
        a[m][ks] = *(const bf16x8_t*)(b + ks * 8192 + (mq * 4 + m) * 1024 + rr * 64 + swzo);
  };
  auto ldB = [&](bf16x8_t (&bv)[2][2], int buf, int nq) {
    const char* b = LDS + 65536 + buf * 32768 + (wc >> 1) * 16384;
    #pragma unroll
    for (int n = 0; n < 2; ++n)
      #pragma unroll
      for (int ks = 0; ks < 2; ++ks)
        bv[n][ks] = *(const bf16x8_t*)(b + ks * 8192 + ((wc & 1) * 4 + nq * 2 + n) * 1024 + rr * 64 + swzo);
  };

  f32x4_t acc[8][4] = {};
  auto mma = [&](bf16x8_t (&a)[4][2], bf16x8_t (&bv)[2][2], int mq, int nq) {
    __builtin_amdgcn_s_setprio(1);
    #pragma unroll
    for (int m = 0; m < 4; ++m)
      #pragma unroll
      for (int n = 0; n < 2; ++n)
        #pragma unroll
        for (int ks = 0; ks < 2; ++ks)
          acc[mq * 4 + m][nq * 2 + n] =
            __builtin_amdgcn_mfma_f32_16x16x32_bf16(a[m][ks], bv[n][ks], acc[mq * 4 + m][nq * 2 + n], 0, 0, 0);
    __builtin_amdgcn_s_setprio(0);
  };

  const int NT = K >> 6;   // K multiple of 64, NT >= 2
  stageA(0, 0); stageB(0, 0); stageA(0, 1); stageB(0, 1);
  if (1 < NT) { stageA(1, 0); stageB(1, 0); }
  if (1 < NT) asm volatile("s_waitcnt vmcnt(4)" ::: "memory");
  else        asm volatile("s_waitcnt vmcnt(0)" ::: "memory");
  __builtin_amdgcn_s_barrier();

  for (int kt = 0; kt < NT; ++kt) {
    const int cur = kt & 1;
    bf16x8_t Alo[4][2], Ahi[4][2], B0[2][2], B1[2][2];
    ldA(Alo, cur, 0); ldB(B0, cur, 0);
    if (kt + 1 < NT) stageA(kt + 1, 1);
    asm volatile("s_waitcnt lgkmcnt(0)" ::: "memory");
    __builtin_amdgcn_sched_barrier(0);
    mma(Alo, B0, 0, 0);
    ldA(Ahi, cur, 1);
    if (kt + 1 < NT) stageB(kt + 1, 1);
    asm volatile("s_waitcnt lgkmcnt(0)" ::: "memory");
    __builtin_amdgcn_sched_barrier(0);
    mma(Ahi, B0, 1, 0);
    __builtin_amdgcn_s_barrier();
    ldB(B1, cur, 1);
    if (kt + 2 < NT) stageA(kt + 2, 0);
    asm volatile("s_waitcnt lgkmcnt(0)" ::: "memory");
    __builtin_amdgcn_sched_barrier(0);
    mma(Ahi, B1, 1, 1);
    if (kt + 2 < NT) stageB(kt + 2, 0);
    mma(Alo, B1, 0, 1);
    if (kt + 1 < NT) {
      if (kt + 2 < NT) asm volatile("s_waitcnt vmcnt(4)" ::: "memory");
      else             asm volatile("s_waitcnt vmcnt(0)" ::: "memory");
    }
    __builtin_amdgcn_s_barrier();
  }

  // epilogue: C/D layout col=lane&15, row=(lane>>4)*4+j — non-temporal stores
  #pragma unroll
  for (int m = 0; m < 8; ++m) {
    #pragma unroll
    for (int j = 0; j < 4; ++j) {
      const int grow = m0 + wr * 128 + m * 16 + kq * 4 + j;
      size_t rowbase;
      if (EP == 1) {
        int bw = grow / 49, nn = grow - bw * 49;
        int b = bw >> 6, wi = bw & 63;
        int hh = (wi >> 3) * 7 + nn / 7 + 3;  if (hh >= 56) hh -= 56;
        int ww2 = (wi & 7) * 7 + (nn % 7) + 3; if (ww2 >= 56) ww2 -= 56;
        rowbase = ((size_t)b * 3136 + hh * 56 + ww2) * 512;
      } else if (EP == 3) {
        rowbase = (size_t)grow * 512;
      } else {
        rowbase = (size_t)grow * Ncols;
      }
      #pragma unroll
      for (int n = 0; n < 4; ++n) {
        const int gcol = n0 + wc * 64 + n * 16 + rr;
        float v = acc[m][n][j] + bias[gcol];
        if (EP == 0) {
          if (gcol < 512) v *= 0.17677669529663687f;  // hd^-0.5
          nts(&obf[rowbase + gcol], v);
        } else if (EP == 1) {
          ntf(&ofp[rowbase + gcol], resid[rowbase + gcol] + v);
        } else if (EP == 2) {
          float u = 0.5f * v * (1.f + erff(v * 0.70710678118f));
          nts(&obf[rowbase + gcol], u);
        } else {
          ntf(&ofp[rowbase + gcol], ofp[rowbase + gcol] + v);
        }
      }
    }
  }
}

extern "C" void kernel_launch(void* const* d_in, const int* in_sizes, int n_in,
                              void* d_out, int out_size, void* d_ws, size_t ws_size,
                              hipStream_t stream) {
  const float* x      = (const float*)d_in[0];
  const int*   rpi    = (const int*)  d_in[1];
  const float* amask  = (const float*)d_in[2];
  const float* n1g    = (const float*)d_in[3];
  const float* n1b    = (const float*)d_in[4];
  const float* qkv_w  = (const float*)d_in[5];
  const float* qkv_b  = (const float*)d_in[6];
  const float* proj_w = (const float*)d_in[7];
  const float* proj_b = (const float*)d_in[8];
  const float* rpb_t  = (const float*)d_in[9];
  const float* n2g    = (const float*)d_in[10];
  const float* n2b    = (const float*)d_in[11];
  const float* w1     = (const float*)d_in[12];
  const float* b1     = (const float*)d_in[13];
  const float* w2     = (const float*)d_in[14];
  const float* b2     = (const float*)d_in[15];
  float* out = (float*)d_out;

  char* ws = (char*)d_ws;
  const size_t M = 50176;
  const size_t szA = M * 2048 * 2;          // region A: xw -> o -> m   (tail reused for cmbp)
  const size_t szB = M * 1536 * 2;          // region B: qkv -> h2
  const size_t offB = szA;
  const size_t offW = offB + szB;
  __hip_bfloat16* bufA = (__hip_bfloat16*)(ws);
  __hip_bfloat16* bufB = (__hip_bfloat16*)(ws + offB);
  __hip_bfloat16* wqkv  = (__hip_bfloat16*)(ws + offW);
  __hip_bfloat16* wproj = wqkv + 786432;
  __hip_bfloat16* wm1   = wproj + 262144;
  __hip_bfloat16* wm2   = wm1 + 1048576;
  float* cmbp = (float*)(ws + szA - (size_t)4194304 * 4);

  k_cvt<<<3072, 256, 0, stream>>>(qkv_w, wqkv, 786432);
  k_cvt<<<1024, 256, 0, stream>>>(proj_w, wproj, 262144);
  k_cvt<<<4096, 256, 0, stream>>>(w1, wm1, 1048576);
  k_cvt<<<4096, 256, 0, stream>>>(w2, wm2, 1048576);
  k_cmb<<<16384, 256, 0, stream>>>(rpi, rpb_t, amask, cmbp);

  // LN1 + shift + window partition -> bufA (bf16, [50176][512])
  k_ln<1><<<50176, 256, 0, stream>>>(x, n1g, n1b, bufA);
  // QKV: bufA @ wqkv^T -> bufB (bf16, [50176][1536], q pre-scaled)
  gemm256<0><<<196 * 6, 512, 0, stream>>>(bufA, wqkv, 512, 1536, 6, qkv_b, bufB, nullptr, nullptr);
  // MFMA attention -> bufA (bf16, [50176][512])
  k_attn<<<dim3(1024, 4), 256, 0, stream>>>(bufB, cmbp, bufA);
  // proj + window reverse + unshift + residual -> d_out (f32)
  gemm256<1><<<196 * 2, 512, 0, stream>>>(bufA, wproj, 512, 512, 2, proj_b, nullptr, x, out);
  // LN2 -> bufB (bf16, [50176][512])
  k_ln<0><<<50176, 256, 0, stream>>>(out, n2g, n2b, bufB);
  // MLP1 + GELU -> bufA (bf16, [50176][2048])
  gemm256<2><<<196 * 8, 512, 0, stream>>>(bufB, wm1, 512, 2048, 8, b1, bufA, nullptr, nullptr);
  // MLP2 + residual accumulate -> d_out
  gemm256<3><<<196 * 2, 512, 0, stream>>>(bufA, wm2, 2048, 512, 2, b2, nullptr, nullptr, out);
}

// Round 12
// 761.864 us; speedup vs baseline: 1.1172x; 1.1172x over previous
//
#include <hip/hip_runtime.h>
#include <hip/hip_bf16.h>

typedef __attribute__((ext_vector_type(8))) short bf16x8_t;
typedef __attribute__((ext_vector_type(4))) float f32x4_t;

__device__ __forceinline__ void gll16(const void* g, void* l) {
  __builtin_amdgcn_global_load_lds((const __attribute__((address_space(1))) void*)g,
                                   (__attribute__((address_space(3))) void*)l, 16, 0, 0);
}

// ---------------- fused f32 -> bf16 weight convert (dst regions contiguous) ----------------
__global__ __launch_bounds__(256) void k_cvt4(const float* __restrict__ s0, const float* __restrict__ s1,
                                              const float* __restrict__ s2, const float* __restrict__ s3,
                                              __hip_bfloat16* __restrict__ out) {
  int i4 = blockIdx.x * 256 + threadIdx.x;          // float4 index, total 786432
  int i = i4 * 4;
  const float* src;
  int off;
  if (i < 786432)       { src = s0; off = i; }
  else if (i < 1048576) { src = s1; off = i - 786432; }
  else if (i < 2097152) { src = s2; off = i - 1048576; }
  else                  { src = s3; off = i - 2097152; }
  float4 v = *(const float4*)(src + off);
  union { __hip_bfloat16 h[4]; ushort2 u2[2]; } pk;
  pk.h[0] = __float2bfloat16(v.x); pk.h[1] = __float2bfloat16(v.y);
  pk.h[2] = __float2bfloat16(v.z); pk.h[3] = __float2bfloat16(v.w);
  *(ushort2*)(out + i) = pk.u2[0];
  *(ushort2*)(out + i + 2) = pk.u2[1];
}

// ---------------- cmbp: rpb+mask packed in MFMA C-fragment order ----------------
__global__ __launch_bounds__(256) void k_cmb(const int* __restrict__ rpi,
                                             const float* __restrict__ tab,
                                             const float* __restrict__ mask,
                                             float* __restrict__ cmbp) {
  int idx = blockIdx.x * 256 + threadIdx.x;   // < 64*16*16*256 = 4194304
  int jj = idx & 3, lane = (idx >> 2) & 63, tile = (idx >> 8) & 15;
  int h = (idx >> 12) & 15, w6 = idx >> 16;
  int r = (tile >> 2) * 16 + (lane >> 4) * 4 + jj;
  int c = (tile & 3) * 16 + (lane & 15);
  float v = -1e9f;
  if (r < 49 && c < 49) v = tab[rpi[r * 49 + c] * 16 + h] + mask[w6 * 2401 + r * 49 + c];
  cmbp[idx] = v;
}

// ---------------- layernorm, one WAVE per token (no LDS, no block barrier) ----------------
template<int PERM>
__global__ __launch_bounds__(256) void k_ln(const float* __restrict__ in,
                                            const float* __restrict__ g,
                                            const float* __restrict__ bta,
                                            __hip_bfloat16* __restrict__ out) {
  const int w = threadIdx.x >> 6, l = threadIdx.x & 63;
  const int token = blockIdx.x * 4 + w;
  const float4* p = (const float4*)(in + (size_t)token * 512);
  float4 v0 = p[l], v1 = p[l + 64];
  float s  = v0.x + v0.y + v0.z + v0.w + v1.x + v1.y + v1.z + v1.w;
  float sq = v0.x*v0.x + v0.y*v0.y + v0.z*v0.z + v0.w*v0.w
           + v1.x*v1.x + v1.y*v1.y + v1.z*v1.z + v1.w*v1.w;
  #pragma unroll
  for (int d = 1; d < 64; d <<= 1) { s += __shfl_xor(s, d); sq += __shfl_xor(sq, d); }
  float mean = s * (1.f / 512.f);
  float inv = rsqrtf(sq * (1.f / 512.f) - mean * mean + 1e-5f);
  size_t dst;
  if (PERM) {
    int b = token / 3136, pp = token - b * 3136;
    int i = pp / 56, j = pp - i * 56;
    int gi = (i + 53) % 56, gj = (j + 53) % 56;       // (i-3) mod 56
    dst = ((size_t)(((b * 64) + (gi / 7) * 8 + (gj / 7)) * 49) + (gi % 7) * 7 + (gj % 7)) * 512;
  } else {
    dst = (size_t)token * 512;
  }
  int c0 = l * 4, c1 = 256 + l * 4;
  union { __hip_bfloat16 h[4]; ushort4 u4; } a, b4;
  a.h[0] = __float2bfloat16((v0.x - mean) * inv * g[c0]     + bta[c0]);
  a.h[1] = __float2bfloat16((v0.y - mean) * inv * g[c0 + 1] + bta[c0 + 1]);
  a.h[2] = __float2bfloat16((v0.z - mean) * inv * g[c0 + 2] + bta[c0 + 2]);
  a.h[3] = __float2bfloat16((v0.w - mean) * inv * g[c0 + 3] + bta[c0 + 3]);
  b4.h[0] = __float2bfloat16((v1.x - mean) * inv * g[c1]     + bta[c1]);
  b4.h[1] = __float2bfloat16((v1.y - mean) * inv * g[c1 + 1] + bta[c1 + 1]);
  b4.h[2] = __float2bfloat16((v1.z - mean) * inv * g[c1 + 2] + bta[c1 + 2]);
  b4.h[3] = __float2bfloat16((v1.w - mean) * inv * g[c1 + 3] + bta[c1 + 3]);
  *(ushort4*)(out + dst + c0) = a.u4;
  *(ushort4*)(out + dst + c1) = b4.u4;
}

// ---------------- MFMA windowed attention: one wave per (window, head) ----------------
__global__ __launch_bounds__(256) void k_attn(const __hip_bfloat16* __restrict__ qkv,
                                              const float* __restrict__ cmbp,
                                              __hip_bfloat16* __restrict__ o) {
  __shared__ __align__(16) __hip_bfloat16 vt_all[4 * 32 * 72];
  __shared__ __align__(16) __hip_bfloat16 P_all[4 * 64 * 72];
  const int t = threadIdx.x, l = t & 63, w = t >> 6;
  const int bw = blockIdx.x;
  const int head = blockIdx.y * 4 + w;
  const int rr = l & 15, g = l >> 4;
  __hip_bfloat16* vt = vt_all + w * (32 * 72);
  __hip_bfloat16* P  = P_all  + w * (64 * 72);
  const __hip_bfloat16* base = qkv + (size_t)bw * 49 * 1536 + head * 32;
  const bf16x8_t zero8 = {};

  { int d = l >> 1, sg = (l & 1) * 8;
    *(bf16x8_t*)(vt + d * 72 + 48 + sg) = zero8; }
  __builtin_amdgcn_sched_barrier(0);
  #pragma unroll
  for (int it = 0; it < 4; ++it) {
    int idx = l + it * 64;
    if (idx < 196) {
      int j = idx >> 2, sg = (idx & 3) * 8;
      bf16x8_t vv = *(const bf16x8_t*)(base + 1024 + (size_t)j * 1536 + sg);
      #pragma unroll
      for (int s2 = 0; s2 < 8; ++s2) vt[(sg + s2) * 72 + j] = ((__hip_bfloat16*)&vv)[s2];
    }
  }
  bf16x8_t aq[4], bk[4];
  #pragma unroll
  for (int m = 0; m < 4; ++m) {
    int row = m * 16 + rr;
    aq[m] = (row < 49) ? *(const bf16x8_t*)(base + (size_t)row * 1536 + g * 8) : zero8;
    bk[m] = (row < 49) ? *(const bf16x8_t*)(base + 512 + (size_t)row * 1536 + g * 8) : zero8;
  }
  const float4* cp = (const float4*)(cmbp + (size_t)((bw & 63) * 16 + head) * 4096);
  f32x4_t S[4][4];
  #pragma unroll
  for (int tm = 0; tm < 4; ++tm)
    #pragma unroll
    for (int tn = 0; tn < 4; ++tn) {
      float4 cv = cp[(tm * 4 + tn) * 64 + l];
      f32x4_t c0 = { cv.x, cv.y, cv.z, cv.w };
      S[tm][tn] = __builtin_amdgcn_mfma_f32_16x16x32_bf16(aq[tm], bk[tn], c0, 0, 0, 0);
    }
  float sm[4][4];
  #pragma unroll
  for (int tm = 0; tm < 4; ++tm) {
    #pragma unroll
    for (int jj = 0; jj < 4; ++jj) {
      float v = fmaxf(fmaxf(S[tm][0][jj], S[tm][1][jj]), fmaxf(S[tm][2][jj], S[tm][3][jj]));
      v = fmaxf(v, __shfl_xor(v, 1));
      v = fmaxf(v, __shfl_xor(v, 2));
      v = fmaxf(v, __shfl_xor(v, 4));
      v = fmaxf(v, __shfl_xor(v, 8));
      float s = 0.f;
      #pragma unroll
      for (int tn = 0; tn < 4; ++tn) {
        float e = __expf(S[tm][tn][jj] - v);
        S[tm][tn][jj] = e;
        s += e;
      }
      s += __shfl_xor(s, 1); s += __shfl_xor(s, 2); s += __shfl_xor(s, 4); s += __shfl_xor(s, 8);
      sm[tm][jj] = s;
    }
  }
  #pragma unroll
  for (int tm = 0; tm < 4; ++tm)
    #pragma unroll
    for (int tn = 0; tn < 4; ++tn)
      #pragma unroll
      for (int jj = 0; jj < 4; ++jj)
        P[(tm * 16 + g * 4 + jj) * 72 + tn * 16 + rr] = __float2bfloat16(S[tm][tn][jj]);

  f32x4_t O[4][2] = {};
  #pragma unroll
  for (int ks = 0; ks < 2; ++ks) {
    bf16x8_t pa[4], vb[2];
    #pragma unroll
    for (int tm = 0; tm < 4; ++tm)
      pa[tm] = *(const bf16x8_t*)(P + (tm * 16 + rr) * 72 + ks * 32 + g * 8);
    #pragma unroll
    for (int tn = 0; tn < 2; ++tn)
      vb[tn] = *(const bf16x8_t*)(vt + (tn * 16 + rr) * 72 + ks * 32 + g * 8);
    #pragma unroll
    for (int tm = 0; tm < 4; ++tm)
      #pragma unroll
      for (int tn = 0; tn < 2; ++tn)
        O[tm][tn] = __builtin_amdgcn_mfma_f32_16x16x32_bf16(pa[tm], vb[tn], O[tm][tn], 0, 0, 0);
  }
  #pragma unroll
  for (int tm = 0; tm < 4; ++tm) {
    #pragma unroll
    for (int jj = 0; jj < 4; ++jj) {
      int r = tm * 16 + g * 4 + jj;
      if (r < 49) {
        float rcp = 1.f / sm[tm][jj];
        size_t ob = ((size_t)bw * 49 + r) * 512 + head * 32;
        o[ob + rr]      = __float2bfloat16(O[tm][0][jj] * rcp);
        o[ob + 16 + rr] = __float2bfloat16(O[tm][1][jj] * rcp);
      }
    }
  }
}

// ---------------- 256x256 bf16 GEMM: BK=64 quadrant pipeline, counted vmcnt(4),
// NO intra-phase lgkmcnt(0) fences — compiler scoreboards ds_read->MFMA (m97 mechanism).
template<int EP>
__global__ __launch_bounds__(512, 2) void gemm256(const __hip_bfloat16* __restrict__ A,
                                                  const __hip_bfloat16* __restrict__ Bw,
                                                  int K, int Ncols, int nNB,
                                                  const float* __restrict__ bias,
                                                  __hip_bfloat16* __restrict__ obf,
                                                  const float* __restrict__ resid,
                                                  float* __restrict__ ofp) {
  __shared__ __align__(16) char LDS[131072];  // A: [2buf][2half][16KB] at 0; B same at 65536
  const int nwg = gridDim.x, orig = blockIdx.x;
  const int q8 = nwg >> 3, r8 = nwg & 7;
  const int xcd = orig & 7, lin = orig >> 3;
  const int wgid = (xcd < r8 ? xcd * (q8 + 1) : r8 * (q8 + 1) + (xcd - r8) * q8) + lin;
  const int bx = wgid / nNB, by = wgid - bx * nNB;
  const int m0 = bx * 256, n0 = by * 256;
  const int t = threadIdx.x, l = t & 63, w = t >> 6;
  const int wr = w >> 2, wc = w & 3;
  const int rr = l & 15, kq = l >> 4;
  const int swzo = (kq * 16) ^ ((rr & 8) << 2);

  int rs0, cs0, rs1, cs1;
  { int d = t * 16;  rs0 = (d >> 10) * 16 + ((d >> 6) & 15);
    cs0 = ((d & 63) ^ (((d >> 9) & 1) << 5)) >> 1; }
  { int d = 8192 + t * 16; int dd = d & 8191;
    rs1 = (dd >> 10) * 16 + ((dd >> 6) & 15);
    cs1 = 32 + (((d & 63) ^ (((d >> 9) & 1) << 5)) >> 1); }
  const __hip_bfloat16* gA = A + (size_t)m0 * K;
  const __hip_bfloat16* gB = Bw + (size_t)n0 * K;

  auto stageA = [&](int T, int h) {
    char* dst = LDS + (T & 1) * 32768 + h * 16384 + t * 16;
    const size_t kb = (size_t)T * 64;
    gll16(gA + (size_t)(h * 128 + rs0) * K + kb + cs0, dst);
    gll16(gA + (size_t)(h * 128 + rs1) * K + kb + cs1, dst + 8192);
  };
  auto stageB = [&](int T, int h) {
    char* dst = LDS + 65536 + (T & 1) * 32768 + h * 16384 + t * 16;
    const size_t kb = (size_t)T * 64;
    gll16(gB + (size_t)(h * 128 + rs0) * K + kb + cs0, dst);
    gll16(gB + (size_t)(h * 128 + rs1) * K + kb + cs1, dst + 8192);
  };

  auto ldA = [&](bf16x8_t (&a)[4][2], int buf, int mq) {
    const char* b = LDS + buf * 32768 + wr * 16384;
    #pragma unroll
    for (int m = 0; m < 4; ++m)
      #pragma unroll
      for (int ks = 0; ks < 2; ++ks)
        a[m][ks] = *(const bf16x8_t*)(b + ks * 8192 + (mq * 4 + m) * 1024 + rr * 64 + swzo);
  };
  auto ldB = [&](bf16x8_t (&bv)[2][2], int buf, int nq) {
    const char* b = LDS + 65536 + buf * 32768 + (wc >> 1) * 16384;
    #pragma unroll
    for (int n = 0; n < 2; ++n)
      #pragma unroll
      for (int ks = 0; ks < 2; ++ks)
        bv[n][ks] = *(const bf16x8_t*)(b + ks * 8192 + ((wc & 1) * 4 + nq * 2 + n) * 1024 + rr * 64 + swzo);
  };

  f32x4_t acc[8][4] = {};
  auto mma = [&](bf16x8_t (&a)[4][2], bf16x8_t (&bv)[2][2], int mq, int nq) {
    __builtin_amdgcn_s_setprio(1);
    #pragma unroll
    for (int m = 0; m < 4; ++m)
      #pragma unroll
      for (int n = 0; n < 2; ++n)
        #pragma unroll
        for (int ks = 0; ks < 2; ++ks)
          acc[mq * 4 + m][nq * 2 + n] =
            __builtin_amdgcn_mfma_f32_16x16x32_bf16(a[m][ks], bv[n][ks], acc[mq * 4 + m][nq * 2 + n], 0, 0, 0);
    __builtin_amdgcn_s_setprio(0);
  };

  const int NT = K >> 6;   // K multiple of 64, NT >= 2
  stageA(0, 0); stageB(0, 0); stageA(0, 1); stageB(0, 1);
  if (1 < NT) { stageA(1, 0); stageB(1, 0); }
  if (1 < NT) asm volatile("s_waitcnt vmcnt(4)" ::: "memory");
  else        asm volatile("s_waitcnt vmcnt(0)" ::: "memory");
  __builtin_amdgcn_s_barrier();

  for (int kt = 0; kt < NT; ++kt) {
    const int cur = kt & 1;
    bf16x8_t Alo[4][2], Ahi[4][2], B0[2][2], B1[2][2];
    // ph1
    ldA(Alo, cur, 0); ldB(B0, cur, 0);
    if (kt + 1 < NT) stageA(kt + 1, 1);
    mma(Alo, B0, 0, 0);
    // ph2
    ldA(Ahi, cur, 1);
    if (kt + 1 < NT) stageB(kt + 1, 1);
    mma(Ahi, B0, 1, 0);
    __builtin_amdgcn_s_barrier();          // mid: lo-regions of buf[cur] reusable
    // ph3
    ldB(B1, cur, 1);
    if (kt + 2 < NT) stageA(kt + 2, 0);
    mma(Ahi, B1, 1, 1);
    // ph4 (register reuse, no LDS reads)
    if (kt + 2 < NT) stageB(kt + 2, 0);
    mma(Alo, B1, 0, 1);
    if (kt + 1 < NT) {
      if (kt + 2 < NT) asm volatile("s_waitcnt vmcnt(4)" ::: "memory");
      else             asm volatile("s_waitcnt vmcnt(0)" ::: "memory");
    }
    __builtin_amdgcn_s_barrier();
  }

  // epilogue: C/D layout col=lane&15, row=(lane>>4)*4+j
  #pragma unroll
  for (int m = 0; m < 8; ++m) {
    #pragma unroll
    for (int n = 0; n < 4; ++n) {
      const int gcol = n0 + wc * 64 + n * 16 + rr;
      #pragma unroll
      for (int j = 0; j < 4; ++j) {
        const int grow = m0 + wr * 128 + m * 16 + kq * 4 + j;
        float v = acc[m][n][j] + bias[gcol];
        if (EP == 0) {
          if (gcol < 512) v *= 0.17677669529663687f;  // hd^-0.5
          obf[(size_t)grow * Ncols + gcol] = __float2bfloat16(v);
        } else if (EP == 1) {
          int bw = grow / 49, nn = grow - bw * 49;
          int b = bw >> 6, wi = bw & 63;
          int hh = (wi >> 3) * 7 + nn / 7 + 3;  if (hh >= 56) hh -= 56;
          int ww2 = (wi & 7) * 7 + (nn % 7) + 3; if (ww2 >= 56) ww2 -= 56;
          size_t tok = (size_t)b * 3136 + hh * 56 + ww2;
          ofp[tok * 512 + gcol] = resid[tok * 512 + gcol] + v;
        } else if (EP == 2) {
          float u = 0.5f * v * (1.f + erff(v * 0.70710678118f));
          obf[(size_t)grow * Ncols + gcol] = __float2bfloat16(u);
        } else {
          ofp[(size_t)grow * 512 + gcol] += v;
        }
      }
    }
  }
}

extern "C" void kernel_launch(void* const* d_in, const int* in_sizes, int n_in,
                              void* d_out, int out_size, void* d_ws, size_t ws_size,
                              hipStream_t stream) {
  const float* x      = (const float*)d_in[0];
  const int*   rpi    = (const int*)  d_in[1];
  const float* amask  = (const float*)d_in[2];
  const float* n1g    = (const float*)d_in[3];
  const float* n1b    = (const float*)d_in[4];
  const float* qkv_w  = (const float*)d_in[5];
  const float* qkv_b  = (const float*)d_in[6];
  const float* proj_w = (const float*)d_in[7];
  const float* proj_b = (const float*)d_in[8];
  const float* rpb_t  = (const float*)d_in[9];
  const float* n2g    = (const float*)d_in[10];
  const float* n2b    = (const float*)d_in[11];
  const float* w1     = (const float*)d_in[12];
  const float* b1     = (const float*)d_in[13];
  const float* w2     = (const float*)d_in[14];
  const float* b2     = (const float*)d_in[15];
  float* out = (float*)d_out;

  char* ws = (char*)d_ws;
  const size_t M = 50176;
  const size_t szA = M * 2048 * 2;          // region A: xw -> o -> m   (tail reused for cmbp)
  const size_t szB = M * 1536 * 2;          // region B: qkv -> h2
  const size_t offB = szA;
  const size_t offW = offB + szB;
  __hip_bfloat16* bufA = (__hip_bfloat16*)(ws);
  __hip_bfloat16* bufB = (__hip_bfloat16*)(ws + offB);
  __hip_bfloat16* wqkv  = (__hip_bfloat16*)(ws + offW);
  float* cmbp = (float*)(ws + szA - (size_t)4194304 * 4);
  __hip_bfloat16* wproj = wqkv + 786432;
  __hip_bfloat16* wm1   = wproj + 262144;
  __hip_bfloat16* wm2   = wm1 + 1048576;

  // fused weight convert: dst = wqkv..wm2 contiguous (3,145,728 bf16)
  k_cvt4<<<3072, 256, 0, stream>>>(qkv_w, proj_w, w1, w2, wqkv);
  k_cmb<<<16384, 256, 0, stream>>>(rpi, rpb_t, amask, cmbp);

  // LN1 + shift + window partition -> bufA (bf16, [50176][512])
  k_ln<1><<<12544, 256, 0, stream>>>(x, n1g, n1b, bufA);
  // QKV: bufA @ wqkv^T -> bufB (bf16, [50176][1536], q pre-scaled)
  gemm256<0><<<196 * 6, 512, 0, stream>>>(bufA, wqkv, 512, 1536, 6, qkv_b, bufB, nullptr, nullptr);
  // MFMA attention -> bufA (bf16, [50176][512])
  k_attn<<<dim3(1024, 4), 256, 0, stream>>>(bufB, cmbp, bufA);
  // proj + window reverse + unshift + residual -> d_out (f32)
  gemm256<1><<<196 * 2, 512, 0, stream>>>(bufA, wproj, 512, 512, 2, proj_b, nullptr, x, out);
  // LN2 -> bufB (bf16, [50176][512])
  k_ln<0><<<12544, 256, 0, stream>>>(out, n2g, n2b, bufB);
  // MLP1 + GELU -> bufA (bf16, [50176][2048])
  gemm256<2><<<196 * 8, 512, 0, stream>>>(bufB, wm1, 512, 2048, 8, b1, bufA, nullptr, nullptr);
  // MLP2 + residual accumulate -> d_out
  gemm256<3><<<196 * 2, 512, 0, stream>>>(bufA, wm2, 2048, 512, 2, b2, nullptr, nullptr, out);
}